// Round 1
// baseline (585.388 us; speedup 1.0000x reference)
//
#include <hip/hip_runtime.h>
#include <hip/hip_bf16.h>

// ---------- types ----------
typedef __attribute__((ext_vector_type(8))) short bf8_t;   // 8 bf16 in 4 VGPRs
typedef __attribute__((ext_vector_type(4))) float f4_t;    // MFMA accumulator

#define MFMA16(a, b, c) __builtin_amdgcn_mfma_f32_16x16x32_bf16((a), (b), (c), 0, 0, 0)

static __device__ inline unsigned short f2bf(float f) {
    // round-to-nearest-even fp32 -> bf16
    unsigned int u = __float_as_uint(f);
    unsigned int r = 0x7fffu + ((u >> 16) & 1u);
    return (unsigned short)((u + r) >> 16);
}

// ---------- mask dtype probe ----------
// mask buffer is 8192 elements; first 8192 BYTES are valid under any dtype.
// flag: 0 = int32 {0,1}, 1 = float32 {0.0,1.0}, 2 = bytes (bool/int8)
__global__ void k_probe(const unsigned int* __restrict__ m, int* __restrict__ flag) {
    __shared__ int s_int, s_flt;
    if (threadIdx.x == 0) { s_int = 1; s_flt = 1; }
    __syncthreads();
    int li = 1, lf = 1;
    for (int i = threadIdx.x; i < 2048; i += 256) {
        unsigned int w = m[i];
        if (w != 0u && w != 1u) li = 0;
        if (w != 0u && w != 0x3F800000u) lf = 0;
    }
    if (!li) atomicAnd(&s_int, 0);
    if (!lf) atomicAnd(&s_flt, 0);
    __syncthreads();
    if (threadIdx.x == 0) *flag = s_int ? 0 : (s_flt ? 1 : 2);
}

// ---------- fp32 -> bf16 convert (x) ----------
__global__ void k_cvt(const float* __restrict__ x, unsigned short* __restrict__ xb, int n4) {
    int i = blockIdx.x * blockDim.x + threadIdx.x;
    if (i < n4) {
        float4 v = ((const float4*)x)[i];
        ushort4 o;
        o.x = f2bf(v.x); o.y = f2bf(v.y); o.z = f2bf(v.z); o.w = f2bf(v.w);
        ((ushort4*)xb)[i] = o;
    }
}

// ---------- W [K][N] fp32 -> WT [N][K] bf16 (4 matrices via blockIdx.z) ----------
__global__ void k_transw(const float* __restrict__ Wq, const float* __restrict__ Wk,
                         const float* __restrict__ Wv, const float* __restrict__ Wo,
                         unsigned short* __restrict__ WT) {
    __shared__ float tile[32][33];
    const float* W = (blockIdx.z == 0) ? Wq : (blockIdx.z == 1) ? Wk : (blockIdx.z == 2) ? Wv : Wo;
    unsigned short* out = WT + (size_t)blockIdx.z * 1024 * 1024;
    int n_r = blockIdx.x * 32 + threadIdx.x;
    int k_r = blockIdx.y * 32 + threadIdx.y;
    #pragma unroll
    for (int j = 0; j < 32; j += 8)
        tile[threadIdx.y + j][threadIdx.x] = W[(size_t)(k_r + j) * 1024 + n_r];
    __syncthreads();
    int k_w = blockIdx.y * 32 + threadIdx.x;
    int n_w = blockIdx.x * 32 + threadIdx.y;
    #pragma unroll
    for (int j = 0; j < 32; j += 8)
        out[(size_t)(n_w + j) * 1024 + k_w] = f2bf(tile[threadIdx.x][threadIdx.y + j]);
}

// ---------- GEMM: C[M=8192][N=1024] = A_bf16 @ WT_bf16^T (+bias) ----------
// 128x128 tile, 4 waves (2x2), BK=32. MODE 0: write bf16 [B,H,S,dh] (QKV, z=0..2).
// MODE 1: write fp32 [M][N] + bias (output proj).
template <int MODE>
__global__ __launch_bounds__(256) void k_gemm(
    const unsigned short* __restrict__ A,    // [8192][1024] bf16
    const unsigned short* __restrict__ WTb,  // [N][K] bf16 (z-indexed in MODE 0)
    const float* __restrict__ b0, const float* __restrict__ b1, const float* __restrict__ b2,
    void* __restrict__ outp)
{
    __shared__ unsigned short Als[128][40];
    __shared__ unsigned short Bls[128][40];
    const int tid  = threadIdx.x;
    const int lane = tid & 63;
    const int w    = tid >> 6;
    const int wr   = w >> 1, wc = w & 1;
    const int lg   = lane >> 4, lr = lane & 15;
    const int bm   = blockIdx.y * 128;
    const int bn   = blockIdx.x * 128;
    const unsigned short* WT = WTb + (MODE == 0 ? (size_t)blockIdx.z * (1024 * 1024) : 0);

    f4_t acc[4][4];
    const f4_t z4 = {0.f, 0.f, 0.f, 0.f};
    #pragma unroll
    for (int i = 0; i < 4; ++i)
        #pragma unroll
        for (int j = 0; j < 4; ++j) acc[i][j] = z4;

    const int srow = tid >> 2;          // 0..63
    const int scol = (tid & 3) * 8;     // 0,8,16,24

    for (int k0 = 0; k0 < 1024; k0 += 32) {
        __syncthreads();
        #pragma unroll
        for (int p = 0; p < 2; ++p) {
            int r = srow + p * 64;
            *(bf8_t*)(&Als[r][scol]) = *(const bf8_t*)(A  + (size_t)(bm + r) * 1024 + k0 + scol);
            *(bf8_t*)(&Bls[r][scol]) = *(const bf8_t*)(WT + (size_t)(bn + r) * 1024 + k0 + scol);
        }
        __syncthreads();

        bf8_t af[4], bfv[4];
        #pragma unroll
        for (int i = 0; i < 4; ++i) af[i]  = *(const bf8_t*)(&Als[wr * 64 + i * 16 + lr][lg * 8]);
        #pragma unroll
        for (int j = 0; j < 4; ++j) bfv[j] = *(const bf8_t*)(&Bls[wc * 64 + j * 16 + lr][lg * 8]);
        #pragma unroll
        for (int i = 0; i < 4; ++i)
            #pragma unroll
            for (int j = 0; j < 4; ++j)
                acc[i][j] = MFMA16(af[i], bfv[j], acc[i][j]);
    }

    if (MODE == 0) {
        unsigned short* O = (unsigned short*)outp + (size_t)blockIdx.z * (8192 * 1024);
        const float* bias = (blockIdx.z == 0) ? b0 : (blockIdx.z == 1) ? b1 : b2;
        #pragma unroll
        for (int i = 0; i < 4; ++i)
            #pragma unroll
            for (int j = 0; j < 4; ++j)
                #pragma unroll
                for (int r = 0; r < 4; ++r) {
                    int row = bm + wr * 64 + i * 16 + lg * 4 + r;  // b*2048 + s
                    int col = bn + wc * 64 + j * 16 + lr;          // h*64 + d
                    float v = acc[i][j][r] + bias[col];
                    int b = row >> 11, s = row & 2047, h = col >> 6, d = col & 63;
                    O[(((size_t)(b * 16 + h)) * 2048 + s) * 64 + d] = f2bf(v);
                }
    } else {
        float* O = (float*)outp;
        #pragma unroll
        for (int i = 0; i < 4; ++i)
            #pragma unroll
            for (int j = 0; j < 4; ++j)
                #pragma unroll
                for (int r = 0; r < 4; ++r) {
                    int row = bm + wr * 64 + i * 16 + lg * 4 + r;
                    int col = bn + wc * 64 + j * 16 + lr;
                    O[(size_t)row * 1024 + col] = acc[i][j][r] + b0[col];
                }
    }
}

// ---------- flash attention: grid (S/64, B*H), 4 waves x 16 q-rows, KBLK=32 ----------
__global__ __launch_bounds__(256) void k_attn(
    const unsigned short* __restrict__ Q,   // [64][2048][64] bf16
    const unsigned short* __restrict__ K,
    const unsigned short* __restrict__ V,
    const void* __restrict__ maskp,
    const int* __restrict__ flagp,
    unsigned short* __restrict__ O)         // [8192][1024] bf16
{
    __shared__ unsigned short vT[64][40];        // V^T tile: [d][key], padded
    __shared__ unsigned short pls[4][16][40];    // per-wave P re-layout buffer
    const int tid  = threadIdx.x;
    const int lane = tid & 63;
    const int w    = tid >> 6;
    const int lg   = lane >> 4, lr = lane & 15;
    const int bh   = blockIdx.y;
    const int b    = bh >> 4, h = bh & 15;
    const int q0   = blockIdx.x * 64;
    const size_t base = (size_t)bh * (2048 * 64);
    const int flag = *flagp;
    const int*           mi = (const int*)maskp;
    const float*         mf = (const float*)maskp;
    const unsigned char* mb = (const unsigned char*)maskp;

    // Q fragments stay in registers for the whole KV sweep
    const bf8_t qf0 = *(const bf8_t*)(Q + base + (size_t)(q0 + w * 16 + lr) * 64 + lg * 8);
    const bf8_t qf1 = *(const bf8_t*)(Q + base + (size_t)(q0 + w * 16 + lr) * 64 + 32 + lg * 8);

    const f4_t z4 = {0.f, 0.f, 0.f, 0.f};
    f4_t oacc[4] = {z4, z4, z4, z4};
    float mrow[4] = {-1e30f, -1e30f, -1e30f, -1e30f};
    float lsum[4] = {0.f, 0.f, 0.f, 0.f};

    const int vkey = tid & 31;
    const int vd0  = (tid >> 5) * 8;

    for (int k0 = 0; k0 < 2048; k0 += 32) {
        __syncthreads();
        {   // stage V tile transposed into LDS
            bf8_t vv = *(const bf8_t*)(V + base + (size_t)(k0 + vkey) * 64 + vd0);
            #pragma unroll
            for (int e = 0; e < 8; ++e) vT[vd0 + e][vkey] = (unsigned short)vv[e];
        }
        __syncthreads();

        // scores: S = Q K^T (K fragments straight from global; L2-resident)
        f4_t s[2];
        #pragma unroll
        for (int jj = 0; jj < 2; ++jj) {
            const unsigned short* kr = K + base + (size_t)(k0 + jj * 16 + lr) * 64;
            bf8_t kf0 = *(const bf8_t*)(kr + lg * 8);
            bf8_t kf1 = *(const bf8_t*)(kr + 32 + lg * 8);
            f4_t zz = z4;
            zz = MFMA16(qf0, kf0, zz);
            zz = MFMA16(qf1, kf1, zz);
            s[jj] = zz;
        }
        // scale + key mask
        #pragma unroll
        for (int jj = 0; jj < 2; ++jj) {
            int midx = b * 2048 + k0 + jj * 16 + lr;
            bool msk = (flag == 0) ? (mi[midx] != 0)
                     : (flag == 1) ? (mf[midx] != 0.0f)
                     :               (mb[midx] != 0);
            #pragma unroll
            for (int r = 0; r < 4; ++r)
                s[jj][r] = msk ? -1e30f : s[jj][r] * 0.125f;
        }
        // online softmax (rows live on 16-lane groups; reduce over key lanes)
        #pragma unroll
        for (int r = 0; r < 4; ++r) {
            float bmax = fmaxf(s[0][r], s[1][r]);
            bmax = fmaxf(bmax, __shfl_xor(bmax, 1));
            bmax = fmaxf(bmax, __shfl_xor(bmax, 2));
            bmax = fmaxf(bmax, __shfl_xor(bmax, 4));
            bmax = fmaxf(bmax, __shfl_xor(bmax, 8));
            float mnew = fmaxf(mrow[r], bmax);
            float c = exp2f((mrow[r] - mnew) * 1.4426950408889634f);
            mrow[r] = mnew;
            float p0 = exp2f((s[0][r] - mnew) * 1.4426950408889634f);
            float p1 = exp2f((s[1][r] - mnew) * 1.4426950408889634f);
            s[0][r] = p0; s[1][r] = p1;
            float bsum = p0 + p1;
            bsum += __shfl_xor(bsum, 1);
            bsum += __shfl_xor(bsum, 2);
            bsum += __shfl_xor(bsum, 4);
            bsum += __shfl_xor(bsum, 8);
            lsum[r] = lsum[r] * c + bsum;
            oacc[0][r] *= c; oacc[1][r] *= c; oacc[2][r] *= c; oacc[3][r] *= c;
        }
        // P -> LDS (D-layout) -> read back as A-fragment for PV
        #pragma unroll
        for (int jj = 0; jj < 2; ++jj)
            #pragma unroll
            for (int r = 0; r < 4; ++r)
                pls[w][lg * 4 + r][jj * 16 + lr] = f2bf(s[jj][r]);

        bf8_t pa = *(const bf8_t*)(&pls[w][lr][lg * 8]);
        #pragma unroll
        for (int nf = 0; nf < 4; ++nf) {
            bf8_t vf = *(const bf8_t*)(&vT[nf * 16 + lr][lg * 8]);
            oacc[nf] = MFMA16(pa, vf, oacc[nf]);
        }
    }

    // normalize + write [B,S,D] bf16
    #pragma unroll
    for (int r = 0; r < 4; ++r) {
        float inv = 1.0f / lsum[r];
        int srow = q0 + w * 16 + lg * 4 + r;
        size_t obase = ((size_t)(b * 2048 + srow)) * 1024 + h * 64;
        #pragma unroll
        for (int nf = 0; nf < 4; ++nf)
            O[obase + nf * 16 + lr] = f2bf(oacc[nf][r] * inv);
    }
}

// ---------- launch ----------
extern "C" void kernel_launch(void* const* d_in, const int* in_sizes, int n_in,
                              void* d_out, int out_size, void* d_ws, size_t ws_size,
                              hipStream_t stream) {
    const float* x  = (const float*)d_in[0];
    const void*  mask = d_in[1];
    const float* Wq = (const float*)d_in[2];
    const float* bq = (const float*)d_in[3];
    const float* Wk = (const float*)d_in[4];
    const float* bk = (const float*)d_in[5];
    const float* Wv = (const float*)d_in[6];
    const float* bv = (const float*)d_in[7];
    const float* Wo = (const float*)d_in[8];
    const float* bo = (const float*)d_in[9];

    char* ws = (char*)d_ws;
    int*            flag  = (int*)(ws + 0);
    unsigned short* xb    = (unsigned short*)(ws + 256);                 // 16 MiB
    unsigned short* wT    = (unsigned short*)(ws + 256 + 16777216);      // 8 MiB (q,k,v,o)
    unsigned short* qkv   = (unsigned short*)(ws + 256 + 25165824);      // 48 MiB (q,k,v)
    unsigned short* attnb = (unsigned short*)(ws + 256 + 75497472);      // 16 MiB

    k_probe<<<1, 256, 0, stream>>>((const unsigned int*)mask, flag);
    k_cvt<<<8192, 256, 0, stream>>>(x, xb, 2097152);
    k_transw<<<dim3(32, 32, 4), dim3(32, 8), 0, stream>>>(Wq, Wk, Wv, Wo, wT);
    k_gemm<0><<<dim3(8, 64, 3), 256, 0, stream>>>(xb, wT, bq, bk, bv, (void*)qkv);
    k_attn<<<dim3(32, 64), 256, 0, stream>>>(qkv, qkv + 8388608, qkv + 16777216,
                                             mask, flag, attnb);
    k_gemm<1><<<dim3(8, 64, 1), 256, 0, stream>>>(attnb, wT + 3145728, bo, bo, bo, d_out);
}